// Round 19
// baseline (181.404 us; speedup 1.0000x reference)
//
#include <hip/hip_runtime.h>
#include <cstdint>

// MixedAttention: attention (8 heads) + trittention (4 heads, cubic scores), T=192, DIM=512.
// Round 31: revert R30's cooperative mega-kernel (launch silently failed under graph
// capture: absmax == max|ref| -> out was never written; also per-XCD L2 coherence risk).
// Base = R29 (verified 138.8us) + fold finale's A-part into attn blocks: out is
// block-diagonal over heads (out = sum_h ao_h@Wo_h^T + z@Wp^T + bias), so each attn block
// multiplies its in-register 64x64 ao tile by the L2-hot Wo k-slice and scatter-adds into
// out (same template as R29's proven z@Wp^T scatter). Bias added by h==0 blocks only.
// aoh tensor deleted; finale = 96 B-blocks only; A's 201 MFLOP hides inside attn_tritt.

#define B_   4
#define T_   192
#define DIM_ 512
#define AH   8
#define CH   4

typedef unsigned short u16;
typedef unsigned int   u32;
typedef __attribute__((ext_vector_type(8))) short short8;
typedef __attribute__((ext_vector_type(4))) float floatx4;
typedef __attribute__((ext_vector_type(4))) int intx4;
typedef __attribute__((ext_vector_type(2))) float f32x2;
typedef __attribute__((ext_vector_type(8))) _Float16 half8;
typedef __attribute__((ext_vector_type(2))) _Float16 half2v;
typedef __attribute__((ext_vector_type(2))) __fp16 fp16x2;

union Frag  { intx4 i; short8 s; };
union FragH { intx4 i; half8 h; };

__device__ __forceinline__ floatx4 mfma16(Frag a, Frag b, floatx4 c) {
    return __builtin_amdgcn_mfma_f32_16x16x32_bf16(a.s, b.s, c, 0, 0, 0);
}
__device__ __forceinline__ floatx4 mfma16h(FragH a, FragH b, floatx4 c) {
    return __builtin_amdgcn_mfma_f32_16x16x32_f16(a.h, b.h, c, 0, 0, 0);
}

__device__ __forceinline__ float fexp2(float x) {
    return __builtin_amdgcn_exp2f(x);   // bare v_exp_f32
}

__device__ __forceinline__ float wave_reduce_sum(float v) {
#pragma unroll
    for (int off = 32; off >= 1; off >>= 1)
        v += __shfl_xor(v, off, 64);
    return v;
}

__device__ __forceinline__ u32 pack_rne(float x, float y) {
    u32 ux = __float_as_uint(x);
    u32 uy = __float_as_uint(y);
    ux += 0x7fffu + ((ux >> 16) & 1u);
    uy += 0x7fffu + ((uy >> 16) & 1u);
    return (ux >> 16) | (uy & 0xffff0000u);
}
__device__ __forceinline__ u16 bf16_rne(float x) {
    u32 u = __float_as_uint(x);
    u += 0x7fffu + ((u >> 16) & 1u);
    return (u16)(u >> 16);
}
__device__ __forceinline__ float bf16f(u16 h) { return __uint_as_float(((u32)h) << 16); }

// fp16 helpers (score path): packed cvt + packed multiply
__device__ __forceinline__ u32 pack_f16(float x, float y) {
    union { fp16x2 h; u32 u; } cv;
    cv.h = __builtin_amdgcn_cvt_pkrtz(x, y);     // v_cvt_pkrtz_f16_f32
    return cv.u;
}
__device__ __forceinline__ u32 mul_h2(u32 a, u32 b) {
    union { u32 u; half2v h; } ua, ub, uw;
    ua.u = a; ub.u = b;
    uw.h = ua.h * ub.h;                          // v_pk_mul_f16
    return uw.u;
}

__device__ __forceinline__ Frag ld_frag8(const u16* p) {
    Frag f;
    uint2 a = *(const uint2*)p;
    uint2 b = *(const uint2*)(p + 4);
    f.i = (intx4){ (int)a.x, (int)a.y, (int)b.x, (int)b.y };
    return f;
}

#define LOG2E 1.44269504088896f

// --------- Fused prep: zero rs1/rt1/out + LayerNorm (0..767) + W transpose (768..1215) -----
__global__ __launch_bounds__(256) void prep_kernel(
    const float* __restrict__ x,
    const float* __restrict__ g1, const float* __restrict__ b1,
    const float* __restrict__ g2, const float* __restrict__ b2,
    u16* __restrict__ x1h, u16* __restrict__ x2h,
    const float* __restrict__ Wqkv, u16* __restrict__ wqh,
    const float* __restrict__ Wab,  u16* __restrict__ wah,
    const float* __restrict__ Wo,   const float* __restrict__ Wp,
    u16* __restrict__ wofh, float* __restrict__ zero_base, float* __restrict__ outz)
{
    __shared__ union { float t[64][65]; float red[4][2]; } u;
    const int tid = threadIdx.x;
    {
        // zero rs1+rt1 (294,912 float4) and out (98,304 float4)
        int gid = blockIdx.x * 256 + tid;
        if (gid < 294912) ((float4*)zero_base)[gid] = make_float4(0.f, 0.f, 0.f, 0.f);
        if (gid < 98304)  ((float4*)outz)[gid]      = make_float4(0.f, 0.f, 0.f, 0.f);
    }
    if (blockIdx.x < 768) {
        int row = blockIdx.x;
        const float2 v = ((const float2*)(x + (size_t)row * DIM_))[tid];
        float s  = v.x + v.y;
        float s2 = v.x * v.x + v.y * v.y;
        s  = wave_reduce_sum(s);
        s2 = wave_reduce_sum(s2);
        int w = tid >> 6;
        if ((tid & 63) == 0) { u.red[w][0] = s; u.red[w][1] = s2; }
        __syncthreads();
        float ts  = u.red[0][0] + u.red[1][0] + u.red[2][0] + u.red[3][0];
        float ts2 = u.red[0][1] + u.red[1][1] + u.red[2][1] + u.red[3][1];
        float mean = ts * (1.0f / DIM_);
        float var  = ts2 * (1.0f / DIM_) - mean * mean;
        float rstd = rsqrtf(var + 1e-5f);
        int c0 = tid * 2;
        float n0 = (v.x - mean) * rstd;
        float n1 = (v.y - mean) * rstd;
        float a0 = n0 * g1[c0] + b1[c0], a1 = n1 * g1[c0 + 1] + b1[c0 + 1];
        float c2 = n0 * g2[c0] + b2[c0], c3 = n1 * g2[c0 + 1] + b2[c0 + 1];
        size_t o = (size_t)row * 256 + tid;
        ((u32*)x1h)[o] = pack_rne(a0, a1);
        ((u32*)x2h)[o] = pack_rne(c2, c3);
        return;
    }
    int id = blockIdx.x - 768;
    const float* W; u16 *H; int K, N, Kout, kofs, tile;
    if (id < 192)      { W = Wqkv; H = wqh;  K = 512; N = 1536; Kout = 512; kofs = 0;   tile = id;       }
    else if (id < 352) { W = Wab;  H = wah;  K = 512; N = 1280; Kout = 512; kofs = 0;   tile = id - 192; }
    else if (id < 416) { W = Wo;   H = wofh; K = 512; N = 512;  Kout = 768; kofs = 0;   tile = id - 352; }
    else               { W = Wp;   H = wofh; K = 256; N = 512;  Kout = 768; kofs = 512; tile = id - 416; }
    int nx = N >> 6;
    int n0 = (tile % nx) * 64, k0 = (tile / nx) * 64;
    int rr = tid >> 4, c4 = (tid & 15) << 2;
#pragma unroll
    for (int p = 0; p < 4; ++p) {
        int row = rr + p * 16;
        float4 v = *(const float4*)(W + (size_t)(k0 + row) * N + n0 + c4);
        u.t[row][c4 + 0] = v.x; u.t[row][c4 + 1] = v.y;
        u.t[row][c4 + 2] = v.z; u.t[row][c4 + 3] = v.w;
    }
    __syncthreads();
#pragma unroll
    for (int p = 0; p < 4; ++p) {
        int n = rr + p * 16;
        u16 hi[4];
#pragma unroll
        for (int c = 0; c < 4; ++c)
            hi[c] = bf16_rne(u.t[c4 + c][n]);
        size_t o = (size_t)(n0 + n) * Kout + kofs + k0 + c4;
        *(uint2*)&H[o] = make_uint2((u32)hi[0] | ((u32)hi[1] << 16), (u32)hi[2] | ((u32)hi[3] << 16));
    }
}

// ------- Block-diagonal fused input GEMMs (single-pass): C = Ah @ Bh^T (+bias) -------
__global__ __launch_bounds__(256) void gemm_dual(
    const u16* __restrict__ x1h, const u16* __restrict__ wqh,
    const u16* __restrict__ x2h, const u16* __restrict__ wah,
    const float* __restrict__ babcde,
    float* __restrict__ qkv, float* __restrict__ proj)
{
    __shared__ u16 As[64][68];
    __shared__ u16 Bs[64][68];
    const int tid = threadIdx.x;
    const int nb = blockIdx.x;
    const u16 *Ah, *BTh; const float* bias; float* C; int N, bn;
    if (nb < 24) { Ah = x1h; BTh = wqh; bias = nullptr; C = qkv;  N = 1536; bn = nb * 64; }
    else         { Ah = x2h; BTh = wah; bias = babcde; C = proj; N = 1280; bn = (nb - 24) * 64; }
    const int K = 512;
    const int bm = blockIdx.y * 64;
    const int lane = tid & 63, wave = tid >> 6;
    const int m16 = lane & 15, quad = lane >> 4;
    const int wm = (wave >> 1) * 32, wn = (wave & 1) * 32;
    const int r = tid >> 2, c16 = (tid & 3) * 16;

    floatx4 acc[2][2];
#pragma unroll
    for (int i = 0; i < 2; ++i)
#pragma unroll
        for (int j = 0; j < 2; ++j) acc[i][j] = (floatx4){0.f, 0.f, 0.f, 0.f};

    for (int k0 = 0; k0 < K; k0 += 64) {
        __syncthreads();
        {
            const u16* pa = Ah + (size_t)(bm + r) * K + k0 + c16;
            uint4 v0 = *(const uint4*)pa, v1 = *(const uint4*)(pa + 8);
            *(uint2*)&As[r][c16 + 0]  = make_uint2(v0.x, v0.y);
            *(uint2*)&As[r][c16 + 4]  = make_uint2(v0.z, v0.w);
            *(uint2*)&As[r][c16 + 8]  = make_uint2(v1.x, v1.y);
            *(uint2*)&As[r][c16 + 12] = make_uint2(v1.z, v1.w);
        }
        {
            const u16* pb = BTh + (size_t)(bn + r) * K + k0 + c16;
            uint4 v0 = *(const uint4*)pb, v1 = *(const uint4*)(pb + 8);
            *(uint2*)&Bs[r][c16 + 0]  = make_uint2(v0.x, v0.y);
            *(uint2*)&Bs[r][c16 + 4]  = make_uint2(v0.z, v0.w);
            *(uint2*)&Bs[r][c16 + 8]  = make_uint2(v1.x, v1.y);
            *(uint2*)&Bs[r][c16 + 12] = make_uint2(v1.z, v1.w);
        }
        __syncthreads();
#pragma unroll
        for (int ks = 0; ks < 2; ++ks) {
            const int ko = ks * 32 + quad * 8;
            Frag a0 = ld_frag8(&As[wm + m16][ko]);
            Frag a1 = ld_frag8(&As[wm + 16 + m16][ko]);
            Frag b0 = ld_frag8(&Bs[wn + m16][ko]);
            Frag b1 = ld_frag8(&Bs[wn + 16 + m16][ko]);
            acc[0][0] = mfma16(a0, b0, acc[0][0]);
            acc[0][1] = mfma16(a0, b1, acc[0][1]);
            acc[1][0] = mfma16(a1, b0, acc[1][0]);
            acc[1][1] = mfma16(a1, b1, acc[1][1]);
        }
    }
#pragma unroll
    for (int i = 0; i < 2; ++i)
#pragma unroll
        for (int rr = 0; rr < 4; ++rr) {
            int m = bm + wm + i * 16 + quad * 4 + rr;
#pragma unroll
            for (int j = 0; j < 2; ++j) {
                int n = bn + wn + j * 16 + m16;
                float v = acc[i][j][rr];
                if (bias) v += bias[n];
                C[(size_t)m * N + n] = v;
            }
        }
}

// ---------------- Fused attn + tritt (independent; one launch) ----------------
// Blocks 0..95: attention (two K-passes of 96) + in-block out += ao@Wo_h^T (+bias at h==0).
// Blocks 96..1631: trittention (atomic planes). Shared LDS union = 26,496 B.
__global__ __launch_bounds__(256, 3) void attn_tritt(
    const float* __restrict__ qkv, const float* __restrict__ proj,
    const u16* __restrict__ wofh,
    const float* __restrict__ bo, const float* __restrict__ bp,
    float* __restrict__ rs1, float* __restrict__ rt1,
    float* __restrict__ out)
{
    __shared__ union {
        struct {
            union { u16 Ks[96][68]; u16 P[64][100]; u16 oz[64][68]; } kp;  // 13,056 B
            u16 Vt[64][100];                                               // 12,800 B
        } at;
        struct {
            u32 a_lds[48 * 36];
            u32 b_lds[48 * 36];
            float rs_lds[48][33];
            float rt_lds[48][33];
        } tr;                                                              // 26,496 B
    } S;
    const int tid = threadIdx.x;
    const int lane = tid & 63, wave = tid >> 6;
    const int m16 = lane & 15, quad = lane >> 4;

    if (blockIdx.x < 96) {
        // ================= attention path =================
        const int ab = blockIdx.x;
        const int b = ab / 24, rem = ab % 24;
        const int h = rem / 3, qt3 = rem % 3;
        const int qg = wave;
        const size_t base = (size_t)(b * T_) * 1536 + h * 64;

        Frag qf0, qf1;
        {
            const float s = 0.125f * LOG2E;
            const float* qp = qkv + base + (size_t)(qt3 * 64 + qg * 16 + m16) * 1536 + quad * 8;
            float4 u0 = *(const float4*)qp;
            float4 u1 = *(const float4*)(qp + 4);
            float4 u2 = *(const float4*)(qp + 32);
            float4 u3 = *(const float4*)(qp + 36);
            qf0.i = (intx4){ (int)pack_rne(u0.x * s, u0.y * s), (int)pack_rne(u0.z * s, u0.w * s),
                             (int)pack_rne(u1.x * s, u1.y * s), (int)pack_rne(u1.z * s, u1.w * s) };
            qf1.i = (intx4){ (int)pack_rne(u2.x * s, u2.y * s), (int)pack_rne(u2.z * s, u2.w * s),
                             (int)pack_rne(u3.x * s, u3.y * s), (int)pack_rne(u3.z * s, u3.w * s) };
        }

        float rsum[4] = {0.f, 0.f, 0.f, 0.f};
        floatx4 acco[4];
#pragma unroll
        for (int dt = 0; dt < 4; ++dt) acco[dt] = (floatx4){0.f, 0.f, 0.f, 0.f};

        for (int p = 0; p < 2; ++p) {
            if (p) __syncthreads();
            for (int i = tid; i < 96 * 16; i += 256) {
                int row = i >> 4, c4 = (i & 15) << 2;
                const float* kp = qkv + base + (size_t)(p * 96 + row) * 1536 + 512 + c4;
                float4 kv = *(const float4*)kp;
                *(uint2*)&S.at.kp.Ks[row][c4] = make_uint2(pack_rne(kv.x, kv.y), pack_rne(kv.z, kv.w));
                float4 vv = *(const float4*)(qkv + base + (size_t)(p * 96 + row) * 1536 + 1024 + c4);
                S.at.Vt[c4 + 0][row] = bf16_rne(vv.x);
                S.at.Vt[c4 + 1][row] = bf16_rne(vv.y);
                S.at.Vt[c4 + 2][row] = bf16_rne(vv.z);
                S.at.Vt[c4 + 3][row] = bf16_rne(vv.w);
            }
            __syncthreads();

            float ev[6][4];
#pragma unroll
            for (int tt = 0; tt < 6; ++tt) {
                Frag kb0 = ld_frag8(&S.at.kp.Ks[tt * 16 + m16][quad * 8]);
                Frag kb1 = ld_frag8(&S.at.kp.Ks[tt * 16 + m16][32 + quad * 8]);
                floatx4 accs = (floatx4){0.f, 0.f, 0.f, 0.f};
                accs = mfma16(qf0, kb0, accs);
                accs = mfma16(qf1, kb1, accs);
#pragma unroll
                for (int rr = 0; rr < 4; ++rr) {
                    float e = fexp2(accs[rr]);
                    ev[tt][rr] = e;
                    rsum[rr] += e;
                }
            }
            __syncthreads();
#pragma unroll
            for (int tt = 0; tt < 6; ++tt)
#pragma unroll
                for (int rr = 0; rr < 4; ++rr)
                    S.at.kp.P[qg * 16 + quad * 4 + rr][tt * 16 + m16] = bf16_rne(ev[tt][rr]);
#pragma unroll
            for (int ts = 0; ts < 3; ++ts) {
                Frag pf = ld_frag8(&S.at.kp.P[qg * 16 + m16][ts * 32 + quad * 8]);
#pragma unroll
                for (int dt = 0; dt < 4; ++dt) {
                    Frag vf = ld_frag8(&S.at.Vt[dt * 16 + m16][ts * 32 + quad * 8]);
                    acco[dt] = mfma16(pf, vf, acco[dt]);
                }
            }
        }

        float rinv[4];
#pragma unroll
        for (int rr = 0; rr < 4; ++rr) {
            float v = rsum[rr];
            v += __shfl_xor(v, 1, 64);
            v += __shfl_xor(v, 2, 64);
            v += __shfl_xor(v, 4, 64);
            v += __shfl_xor(v, 8, 64);
            rinv[rr] = 1.0f / v;
        }
        // normalized ao tile -> LDS bf16 (oz overlays dead Ks/P region)
        __syncthreads();   // all waves done reading P/Vt for PV
#pragma unroll
        for (int dt = 0; dt < 4; ++dt)
#pragma unroll
            for (int rr = 0; rr < 4; ++rr) {
                float o = acco[dt][rr] * rinv[rr];
                S.at.kp.oz[qg * 16 + quad * 4 + rr][dt * 16 + m16] = bf16_rne(o);
            }
        __syncthreads();
        // out += ao(64x64) @ Wo_h^T (k-slice h*64..h*64+63); bias added once (h==0 blocks)
        const int brow = b * T_ + qt3 * 64;
        const bool addb = (h == 0);
#pragma unroll
        for (int t = 0; t < 8; ++t) {
            const int n0 = wave * 128 + t * 16;
            Frag wo0 = ld_frag8(&wofh[(size_t)(n0 + m16) * 768 + h * 64 + quad * 8]);
            Frag wo1 = ld_frag8(&wofh[(size_t)(n0 + m16) * 768 + h * 64 + 32 + quad * 8]);
#pragma unroll
            for (int qi = 0; qi < 4; ++qi) {
                Frag oa = ld_frag8(&S.at.kp.oz[qi * 16 + m16][quad * 8]);
                Frag ob = ld_frag8(&S.at.kp.oz[qi * 16 + m16][32 + quad * 8]);
                floatx4 ac = (floatx4){0.f, 0.f, 0.f, 0.f};
                ac = mfma16(oa, wo0, ac);
                ac = mfma16(ob, wo1, ac);
#pragma unroll
                for (int rr = 0; rr < 4; ++rr) {
                    int m = brow + qi * 16 + quad * 4 + rr;
                    int n = n0 + m16;
                    float v = ac[rr];
                    if (addb) v += bo[n] + bp[n];
                    unsafeAtomicAdd(&out[(size_t)m * 512 + n], v);
                }
            }
        }
        return;
    }

    // ================= trittention path =================
    const int t2 = blockIdx.x - 96;
    const int xx = t2 % 96;
    const int h = (t2 / 96) % CH;
    const int b = t2 / (96 * CH);
    const int qt = xx >> 4;
    const int sc = (xx >> 2) & 3;
    const int tc = xx & 3;
    const int q0 = qt * 32, s0 = sc * 48, t0 = tc * 48;
    const int bh = b * CH + h;
    const size_t rowbase = (size_t)(b * T_) * 1280 + h * 64;
    const float kA = 0.015625f * LOG2E;

    for (int i = tid; i < 48 * 32; i += 256) {
        int row = i >> 5, cp = i & 31;
        const float2 va = *(const float2*)(proj + rowbase + (size_t)(s0 + row) * 1280 + 0 + cp * 2);
        S.tr.a_lds[row * 36 + cp] = pack_f16(va.x * kA, va.y * kA);
        const float2 vb = *(const float2*)(proj + rowbase + (size_t)(t0 + row) * 1280 + 256 + cp * 2);
        S.tr.b_lds[row * 36 + cp] = pack_f16(vb.x, vb.y);
    }

    FragH cf[2][2];
#pragma unroll
    for (int jq = 0; jq < 2; ++jq) {
        const float* cp = proj + rowbase + (size_t)(q0 + jq * 16 + m16) * 1280 + 512 + quad * 8;
        float4 u0 = *(const float4*)(cp);
        float4 u1 = *(const float4*)(cp + 4);
        float4 u2 = *(const float4*)(cp + 32);
        float4 u3 = *(const float4*)(cp + 36);
        cf[jq][0].i = (intx4){ (int)pack_f16(u0.x, u0.y), (int)pack_f16(u0.z, u0.w),
                               (int)pack_f16(u1.x, u1.y), (int)pack_f16(u1.z, u1.w) };
        cf[jq][1].i = (intx4){ (int)pack_f16(u2.x, u2.y), (int)pack_f16(u2.z, u2.w),
                               (int)pack_f16(u3.x, u3.y), (int)pack_f16(u3.z, u3.w) };
    }
    __syncthreads();

    float rt_acc[3][4][2] = {};

    for (int si = 0; si < 12; ++si) {
        const int srow = wave * 12 + si;
        const intx4 av0 = *(const intx4*)(S.tr.a_lds + srow * 36 + quad * 4);
        const intx4 av1 = *(const intx4*)(S.tr.a_lds + srow * 36 + 16 + quad * 4);
        float rs_s[2] = {0.f, 0.f};
#pragma unroll
        for (int tt = 0; tt < 3; ++tt) {
            const u32* bp2 = S.tr.b_lds + (tt * 16 + m16) * 36;
            intx4 bv0 = *(const intx4*)(bp2 + quad * 4);
            intx4 bv1 = *(const intx4*)(bp2 + 16 + quad * 4);
            FragH w0, w1;
#pragma unroll
            for (int j = 0; j < 4; ++j) {
                w0.i[j] = (int)mul_h2((u32)av0[j], (u32)bv0[j]);
                w1.i[j] = (int)mul_h2((u32)av1[j], (u32)bv1[j]);
            }
#pragma unroll
            for (int jq = 0; jq < 2; ++jq) {
                floatx4 acc = (floatx4){0.f, 0.f, 0.f, 0.f};
                acc = mfma16h(w0, cf[jq][0], acc);
                acc = mfma16h(w1, cf[jq][1], acc);
#pragma unroll
                for (int rr = 0; rr < 4; ++rr) {
                    float e = fexp2(acc[rr]);
                    rt_acc[tt][rr][jq] += e;
                    rs_s[jq] += e;
                }
            }
        }
#pragma unroll
        for (int jq = 0; jq < 2; ++jq) {
            float v = rs_s[jq];
            v += __shfl_xor(v, 16, 64);
            v += __shfl_xor(v, 32, 64);
            if (lane < 16) S.tr.rs_lds[srow][jq * 16 + m16] = v;
        }
    }

    __syncthreads();
    for (int w = 0; w < 4; ++w) {
        if (wave == w) {
#pragma unroll
            for (int tt = 0; tt < 3; ++tt)
#pragma unroll
                for (int rr = 0; rr < 4; ++rr) {
                    int t = tt * 16 + quad * 4 + rr;
#pragma unroll
                    for (int jq = 0; jq < 2; ++jq) {
                        if (w == 0) S.tr.rt_lds[t][jq * 16 + m16] = rt_acc[tt][rr][jq];
                        else        S.tr.rt_lds[t][jq * 16 + m16] += rt_acc[tt][rr][jq];
                    }
                }
        }
        __syncthreads();
    }
    for (int i = tid; i < 32 * 48; i += 256) {
        int qq = i / 48, ss = i - qq * 48;
        unsafeAtomicAdd(&rs1[((size_t)bh * T_ + q0 + qq) * T_ + s0 + ss], S.tr.rs_lds[ss][qq]);
    }
    for (int i = tid; i < 32 * 48; i += 256) {
        int qq = i / 48, t3 = i - qq * 48;
        unsafeAtomicAdd(&rt1[((size_t)bh * T_ + q0 + qq) * T_ + t0 + t3], S.tr.rt_lds[t3][qq]);
    }
}

// ---------------- Finale (B only): zgemm in registers, then out += z @ Wp^T ----------------
__global__ __launch_bounds__(256) void finale(
    const float* __restrict__ rs1, const float* __restrict__ rt1,
    const float* __restrict__ proj, const u16* __restrict__ wofh,
    float* __restrict__ out)
{
    __shared__ struct { u16 Am[2][32][68]; u16 Bs[64][68]; float zred[32][9]; float Zl[32]; } S;
    const int tid = threadIdx.x;
    const int lane = tid & 63, wave = tid >> 6;
    const int m16 = lane & 15, quad = lane >> 4;

    const int blockB = blockIdx.x;
    const int mt = blockB % 6, bh = blockB / 6;
    const int b = bh >> 2, h = bh & 3;
    const int q0 = mt * 32;
    const int wm = (wave >> 1) * 16, wn = (wave & 1) * 32;
    const int ra = tid >> 3, c8 = (tid & 7) * 8;
    const int sl = tid >> 2, d4b = (tid & 3) * 4;

    float zacc = 0.f;
    floatx4 acc[2];
    acc[0] = (floatx4){0.f, 0.f, 0.f, 0.f};
    acc[1] = (floatx4){0.f, 0.f, 0.f, 0.f};

    for (int k0 = 0; k0 < 384; k0 += 64) {
        __syncthreads();
        {
            float g[8];
            if (k0 < 192) {
                const float* p = rs1 + ((size_t)bh * T_ + q0 + ra) * T_ + k0 + c8;
                float4 v0 = *(const float4*)(p);
                float4 v1 = *(const float4*)(p + 4);
                g[0] = v0.x; g[1] = v0.y; g[2] = v0.z; g[3] = v0.w;
                g[4] = v1.x; g[5] = v1.y; g[6] = v1.z; g[7] = v1.w;
                zacc += ((g[0] + g[1]) + (g[2] + g[3])) + ((g[4] + g[5]) + (g[6] + g[7]));
            } else {
                const float* p = rt1 + ((size_t)bh * T_ + q0 + ra) * T_ + (k0 - 192) + c8;
                float4 v0 = *(const float4*)(p);
                float4 v1 = *(const float4*)(p + 4);
                g[0] = v0.x; g[1] = v0.y; g[2] = v0.z; g[3] = v0.w;
                g[4] = v1.x; g[5] = v1.y; g[6] = v1.z; g[7] = v1.w;
            }
#pragma unroll
            for (int i = 0; i < 8; ++i) {
                u16 hi = bf16_rne(g[i]);
                S.Am[0][ra][c8 + i] = hi;
                S.Am[1][ra][c8 + i] = bf16_rne(g[i] - bf16f(hi));
            }
        }
        {
            const int colbase = (k0 < 192 ? 768 : 1024) + h * 64;
            const int s0 = (k0 < 192 ? k0 : k0 - 192);
#pragma unroll
            for (int i = 0; i < 4; ++i) {
                int dd = d4b + i * 16;
                float4 v = *(const float4*)(proj + (size_t)(b * T_ + s0 + sl) * 1280 + colbase + dd);
                S.Bs[dd + 0][sl] = bf16_rne(v.x);
                S.Bs[dd + 1][sl] = bf16_rne(v.y);
                S.Bs[dd + 2][sl] = bf16_rne(v.z);
                S.Bs[dd + 3][sl] = bf16_rne(v.w);
            }
        }
        __syncthreads();
#pragma unroll
        for (int ks = 0; ks < 2; ++ks) {
            const int ko = ks * 32 + quad * 8;
            Frag gh = ld_frag8(&S.Am[0][wm + m16][ko]);
            Frag gl = ld_frag8(&S.Am[1][wm + m16][ko]);
            Frag d0 = ld_frag8(&S.Bs[wn + m16][ko]);
            Frag d1 = ld_frag8(&S.Bs[wn + 16 + m16][ko]);
            acc[0] = mfma16(gh, d0, acc[0]);
            acc[0] = mfma16(gl, d0, acc[0]);
            acc[1] = mfma16(gh, d1, acc[1]);
            acc[1] = mfma16(gl, d1, acc[1]);
        }
    }
    S.zred[ra][tid & 7] = zacc;
    __syncthreads();
    if (tid < 32) {
        float s = ((S.zred[tid][0] + S.zred[tid][1]) + (S.zred[tid][2] + S.zred[tid][3]))
                + ((S.zred[tid][4] + S.zred[tid][5]) + (S.zred[tid][6] + S.zred[tid][7]));
        S.Zl[tid] = 1.0f / s;
    }
    __syncthreads();
    // normalized z tile -> LDS bf16 (reuse Am[0] as z_s[32][68]); then z @ Wp^T scatter
    {
        float zv[2][4];
#pragma unroll
        for (int j = 0; j < 2; ++j)
#pragma unroll
            for (int rr = 0; rr < 4; ++rr) {
                int m = wm + quad * 4 + rr;
                zv[j][rr] = acc[j][rr] * S.Zl[m];
            }
        __syncthreads();
#pragma unroll
        for (int j = 0; j < 2; ++j)
#pragma unroll
            for (int rr = 0; rr < 4; ++rr) {
                int m = wm + quad * 4 + rr;
                int d = wn + j * 16 + m16;
                S.Am[0][m][d] = bf16_rne(zv[j][rr]);
            }
    }
    __syncthreads();
#pragma unroll
    for (int t = 0; t < 8; ++t) {
        const int n0 = wave * 128 + t * 16;
        Frag bf0 = ld_frag8(&wofh[(size_t)(n0 + m16) * 768 + 512 + h * 64 + quad * 8]);
        Frag bf1 = ld_frag8(&wofh[(size_t)(n0 + m16) * 768 + 512 + h * 64 + 32 + quad * 8]);
#pragma unroll
        for (int qi = 0; qi < 2; ++qi) {
            Frag za = ld_frag8(&S.Am[0][qi * 16 + m16][quad * 8]);
            Frag zb = ld_frag8(&S.Am[0][qi * 16 + m16][32 + quad * 8]);
            floatx4 ac = (floatx4){0.f, 0.f, 0.f, 0.f};
            ac = mfma16(za, bf0, ac);
            ac = mfma16(zb, bf1, ac);
#pragma unroll
            for (int rr = 0; rr < 4; ++rr) {
                int m = b * T_ + q0 + qi * 16 + quad * 4 + rr;
                unsafeAtomicAdd(&out[(size_t)m * 512 + n0 + m16], ac[rr]);
            }
        }
    }
}

extern "C" void kernel_launch(void* const* d_in, const int* in_sizes, int n_in,
                              void* d_out, int out_size, void* d_ws, size_t ws_size,
                              hipStream_t stream)
{
    const float* x      = (const float*)d_in[0];
    const float* ln1_g  = (const float*)d_in[1];
    const float* ln1_b  = (const float*)d_in[2];
    const float* Wqkv   = (const float*)d_in[3];
    const float* Wo     = (const float*)d_in[4];
    const float* bo     = (const float*)d_in[5];
    const float* ln2_g  = (const float*)d_in[6];
    const float* ln2_b  = (const float*)d_in[7];
    const float* Wabcde = (const float*)d_in[8];
    const float* babcde = (const float*)d_in[9];
    const float* Wp     = (const float*)d_in[10];
    const float* bp     = (const float*)d_in[11];
    float* out = (float*)d_out;

    // ---- workspace layout (f32 units) — NO aliasing ----
    float* ws   = (float*)d_ws;
    float* proj = ws;                              // 983,040 f
    u16* wofh   = (u16*)(ws + 983040);             // 393,216 u16
    float* qkv  = ws + 1376256;                    // 1,179,648 f
    u16* x1h    = (u16*)(ws + 2555904);            // 393,216 u16
    u16* x2h    = (u16*)(ws + 2752512);            // 393,216 u16
    u16* wqh    = (u16*)(ws + 2949120);            // 786,432 u16
    u16* wah    = (u16*)(ws + 3342336);            // 655,360 u16
    float* rs1  = ws + 3670016;                    // 589,824 f (zeroed by prep)
    float* rt1  = ws + 4259840;                    // 589,824 f (contiguous after rs1)

    prep_kernel<<<1216, 256, 0, stream>>>(x, ln1_g, ln1_b, ln2_g, ln2_b,
                                          x1h, x2h,
                                          Wqkv, wqh, Wabcde, wah,
                                          Wo, Wp, wofh, rs1, out);
    gemm_dual<<<dim3(44, 12), 256, 0, stream>>>(x1h, wqh, x2h, wah,
                                                babcde, qkv, proj);
    attn_tritt<<<96 + 1536, 256, 0, stream>>>(qkv, proj, wofh, bo, bp, rs1, rt1, out);
    finale<<<96, 256, 0, stream>>>(rs1, rt1, proj, wofh, out);
}

// Round 20
// 138.682 us; speedup vs baseline: 1.3081x; 1.3081x over previous
//
#include <hip/hip_runtime.h>
#include <cstdint>

// MixedAttention: attention (8 heads) + trittention (4 heads, cubic scores), T=192, DIM=512.
// Round 32 = R29 verbatim (verified 138.8us) — banking the proven optimum.
// R31's fold of ao@Wo^T into attn blocks regressed (attn_tritt 42->74us: 12.6MB of 8-way
// contended f32 atomics into out + stride-768 wofh gathers + oz bank conflicts). The aoh
// round-trip (0.75MB write + 4.5MB contention-free read) is the cheaper design.
// Pipeline: prep (zero+LN+W^T) -> gemm_dual -> attn_tritt (fused, independent) ->
// finale (A: ao@Wo^T+bias atomic; B: zgemm-in-reg + z@Wp^T atomic). 4 launches.

#define B_   4
#define T_   192
#define DIM_ 512
#define AH   8
#define CH   4

typedef unsigned short u16;
typedef unsigned int   u32;
typedef __attribute__((ext_vector_type(8))) short short8;
typedef __attribute__((ext_vector_type(4))) float floatx4;
typedef __attribute__((ext_vector_type(4))) int intx4;
typedef __attribute__((ext_vector_type(2))) float f32x2;
typedef __attribute__((ext_vector_type(8))) _Float16 half8;
typedef __attribute__((ext_vector_type(2))) _Float16 half2v;
typedef __attribute__((ext_vector_type(2))) __fp16 fp16x2;

union Frag  { intx4 i; short8 s; };
union FragH { intx4 i; half8 h; };

__device__ __forceinline__ floatx4 mfma16(Frag a, Frag b, floatx4 c) {
    return __builtin_amdgcn_mfma_f32_16x16x32_bf16(a.s, b.s, c, 0, 0, 0);
}
__device__ __forceinline__ floatx4 mfma16h(FragH a, FragH b, floatx4 c) {
    return __builtin_amdgcn_mfma_f32_16x16x32_f16(a.h, b.h, c, 0, 0, 0);
}

__device__ __forceinline__ float fexp2(float x) {
    return __builtin_amdgcn_exp2f(x);   // bare v_exp_f32
}

__device__ __forceinline__ float wave_reduce_sum(float v) {
#pragma unroll
    for (int off = 32; off >= 1; off >>= 1)
        v += __shfl_xor(v, off, 64);
    return v;
}

__device__ __forceinline__ u32 pack_rne(float x, float y) {
    u32 ux = __float_as_uint(x);
    u32 uy = __float_as_uint(y);
    ux += 0x7fffu + ((ux >> 16) & 1u);
    uy += 0x7fffu + ((uy >> 16) & 1u);
    return (ux >> 16) | (uy & 0xffff0000u);
}
__device__ __forceinline__ u16 bf16_rne(float x) {
    u32 u = __float_as_uint(x);
    u += 0x7fffu + ((u >> 16) & 1u);
    return (u16)(u >> 16);
}
__device__ __forceinline__ float bf16f(u16 h) { return __uint_as_float(((u32)h) << 16); }

// fp16 helpers (score path): packed cvt + packed multiply
__device__ __forceinline__ u32 pack_f16(float x, float y) {
    union { fp16x2 h; u32 u; } cv;
    cv.h = __builtin_amdgcn_cvt_pkrtz(x, y);     // v_cvt_pkrtz_f16_f32
    return cv.u;
}
__device__ __forceinline__ u32 mul_h2(u32 a, u32 b) {
    union { u32 u; half2v h; } ua, ub, uw;
    ua.u = a; ub.u = b;
    uw.h = ua.h * ub.h;                          // v_pk_mul_f16
    return uw.u;
}

__device__ __forceinline__ Frag ld_frag8(const u16* p) {
    Frag f;
    uint2 a = *(const uint2*)p;
    uint2 b = *(const uint2*)(p + 4);
    f.i = (intx4){ (int)a.x, (int)a.y, (int)b.x, (int)b.y };
    return f;
}

#define LOG2E 1.44269504088896f

// --------- Fused prep: zero rs1/rt1/out + LayerNorm (0..767) + W transpose (768..1215) -----
__global__ __launch_bounds__(256) void prep_kernel(
    const float* __restrict__ x,
    const float* __restrict__ g1, const float* __restrict__ b1,
    const float* __restrict__ g2, const float* __restrict__ b2,
    u16* __restrict__ x1h, u16* __restrict__ x2h,
    const float* __restrict__ Wqkv, u16* __restrict__ wqh,
    const float* __restrict__ Wab,  u16* __restrict__ wah,
    const float* __restrict__ Wo,   const float* __restrict__ Wp,
    u16* __restrict__ wofh, float* __restrict__ zero_base, float* __restrict__ outz)
{
    __shared__ union { float t[64][65]; float red[4][2]; } u;
    const int tid = threadIdx.x;
    {
        // zero rs1+rt1 (294,912 float4) and out (98,304 float4)
        int gid = blockIdx.x * 256 + tid;
        if (gid < 294912) ((float4*)zero_base)[gid] = make_float4(0.f, 0.f, 0.f, 0.f);
        if (gid < 98304)  ((float4*)outz)[gid]      = make_float4(0.f, 0.f, 0.f, 0.f);
    }
    if (blockIdx.x < 768) {
        int row = blockIdx.x;
        const float2 v = ((const float2*)(x + (size_t)row * DIM_))[tid];
        float s  = v.x + v.y;
        float s2 = v.x * v.x + v.y * v.y;
        s  = wave_reduce_sum(s);
        s2 = wave_reduce_sum(s2);
        int w = tid >> 6;
        if ((tid & 63) == 0) { u.red[w][0] = s; u.red[w][1] = s2; }
        __syncthreads();
        float ts  = u.red[0][0] + u.red[1][0] + u.red[2][0] + u.red[3][0];
        float ts2 = u.red[0][1] + u.red[1][1] + u.red[2][1] + u.red[3][1];
        float mean = ts * (1.0f / DIM_);
        float var  = ts2 * (1.0f / DIM_) - mean * mean;
        float rstd = rsqrtf(var + 1e-5f);
        int c0 = tid * 2;
        float n0 = (v.x - mean) * rstd;
        float n1 = (v.y - mean) * rstd;
        float a0 = n0 * g1[c0] + b1[c0], a1 = n1 * g1[c0 + 1] + b1[c0 + 1];
        float c2 = n0 * g2[c0] + b2[c0], c3 = n1 * g2[c0 + 1] + b2[c0 + 1];
        size_t o = (size_t)row * 256 + tid;
        ((u32*)x1h)[o] = pack_rne(a0, a1);
        ((u32*)x2h)[o] = pack_rne(c2, c3);
        return;
    }
    int id = blockIdx.x - 768;
    const float* W; u16 *H; int K, N, Kout, kofs, tile;
    if (id < 192)      { W = Wqkv; H = wqh;  K = 512; N = 1536; Kout = 512; kofs = 0;   tile = id;       }
    else if (id < 352) { W = Wab;  H = wah;  K = 512; N = 1280; Kout = 512; kofs = 0;   tile = id - 192; }
    else if (id < 416) { W = Wo;   H = wofh; K = 512; N = 512;  Kout = 768; kofs = 0;   tile = id - 352; }
    else               { W = Wp;   H = wofh; K = 256; N = 512;  Kout = 768; kofs = 512; tile = id - 416; }
    int nx = N >> 6;
    int n0 = (tile % nx) * 64, k0 = (tile / nx) * 64;
    int rr = tid >> 4, c4 = (tid & 15) << 2;
#pragma unroll
    for (int p = 0; p < 4; ++p) {
        int row = rr + p * 16;
        float4 v = *(const float4*)(W + (size_t)(k0 + row) * N + n0 + c4);
        u.t[row][c4 + 0] = v.x; u.t[row][c4 + 1] = v.y;
        u.t[row][c4 + 2] = v.z; u.t[row][c4 + 3] = v.w;
    }
    __syncthreads();
#pragma unroll
    for (int p = 0; p < 4; ++p) {
        int n = rr + p * 16;
        u16 hi[4];
#pragma unroll
        for (int c = 0; c < 4; ++c)
            hi[c] = bf16_rne(u.t[c4 + c][n]);
        size_t o = (size_t)(n0 + n) * Kout + kofs + k0 + c4;
        *(uint2*)&H[o] = make_uint2((u32)hi[0] | ((u32)hi[1] << 16), (u32)hi[2] | ((u32)hi[3] << 16));
    }
}

// ------- Block-diagonal fused input GEMMs (single-pass): C = Ah @ Bh^T (+bias) -------
__global__ __launch_bounds__(256) void gemm_dual(
    const u16* __restrict__ x1h, const u16* __restrict__ wqh,
    const u16* __restrict__ x2h, const u16* __restrict__ wah,
    const float* __restrict__ babcde,
    float* __restrict__ qkv, float* __restrict__ proj)
{
    __shared__ u16 As[64][68];
    __shared__ u16 Bs[64][68];
    const int tid = threadIdx.x;
    const int nb = blockIdx.x;
    const u16 *Ah, *BTh; const float* bias; float* C; int N, bn;
    if (nb < 24) { Ah = x1h; BTh = wqh; bias = nullptr; C = qkv;  N = 1536; bn = nb * 64; }
    else         { Ah = x2h; BTh = wah; bias = babcde; C = proj; N = 1280; bn = (nb - 24) * 64; }
    const int K = 512;
    const int bm = blockIdx.y * 64;
    const int lane = tid & 63, wave = tid >> 6;
    const int m16 = lane & 15, quad = lane >> 4;
    const int wm = (wave >> 1) * 32, wn = (wave & 1) * 32;
    const int r = tid >> 2, c16 = (tid & 3) * 16;

    floatx4 acc[2][2];
#pragma unroll
    for (int i = 0; i < 2; ++i)
#pragma unroll
        for (int j = 0; j < 2; ++j) acc[i][j] = (floatx4){0.f, 0.f, 0.f, 0.f};

    for (int k0 = 0; k0 < K; k0 += 64) {
        __syncthreads();
        {
            const u16* pa = Ah + (size_t)(bm + r) * K + k0 + c16;
            uint4 v0 = *(const uint4*)pa, v1 = *(const uint4*)(pa + 8);
            *(uint2*)&As[r][c16 + 0]  = make_uint2(v0.x, v0.y);
            *(uint2*)&As[r][c16 + 4]  = make_uint2(v0.z, v0.w);
            *(uint2*)&As[r][c16 + 8]  = make_uint2(v1.x, v1.y);
            *(uint2*)&As[r][c16 + 12] = make_uint2(v1.z, v1.w);
        }
        {
            const u16* pb = BTh + (size_t)(bn + r) * K + k0 + c16;
            uint4 v0 = *(const uint4*)pb, v1 = *(const uint4*)(pb + 8);
            *(uint2*)&Bs[r][c16 + 0]  = make_uint2(v0.x, v0.y);
            *(uint2*)&Bs[r][c16 + 4]  = make_uint2(v0.z, v0.w);
            *(uint2*)&Bs[r][c16 + 8]  = make_uint2(v1.x, v1.y);
            *(uint2*)&Bs[r][c16 + 12] = make_uint2(v1.z, v1.w);
        }
        __syncthreads();
#pragma unroll
        for (int ks = 0; ks < 2; ++ks) {
            const int ko = ks * 32 + quad * 8;
            Frag a0 = ld_frag8(&As[wm + m16][ko]);
            Frag a1 = ld_frag8(&As[wm + 16 + m16][ko]);
            Frag b0 = ld_frag8(&Bs[wn + m16][ko]);
            Frag b1 = ld_frag8(&Bs[wn + 16 + m16][ko]);
            acc[0][0] = mfma16(a0, b0, acc[0][0]);
            acc[0][1] = mfma16(a0, b1, acc[0][1]);
            acc[1][0] = mfma16(a1, b0, acc[1][0]);
            acc[1][1] = mfma16(a1, b1, acc[1][1]);
        }
    }
#pragma unroll
    for (int i = 0; i < 2; ++i)
#pragma unroll
        for (int rr = 0; rr < 4; ++rr) {
            int m = bm + wm + i * 16 + quad * 4 + rr;
#pragma unroll
            for (int j = 0; j < 2; ++j) {
                int n = bn + wn + j * 16 + m16;
                float v = acc[i][j][rr];
                if (bias) v += bias[n];
                C[(size_t)m * N + n] = v;
            }
        }
}

// ---------------- Fused attn + tritt (independent; one launch) ----------------
__global__ __launch_bounds__(256, 3) void attn_tritt(
    const float* __restrict__ qkv, const float* __restrict__ proj,
    u16* __restrict__ aoh, float* __restrict__ rs1, float* __restrict__ rt1)
{
    __shared__ union {
        struct {
            union { u16 Ks[96][68]; u16 P[64][100]; } kp;   // 13,056 B
            u16 Vt[64][100];                                 // 12,800 B
        } at;
        struct {
            u32 a_lds[48 * 36];
            u32 b_lds[48 * 36];
            float rs_lds[48][33];
            float rt_lds[48][33];
        } tr;                                                // 26,496 B
    } S;
    const int tid = threadIdx.x;
    const int lane = tid & 63, wave = tid >> 6;
    const int m16 = lane & 15, quad = lane >> 4;

    if (blockIdx.x < 96) {
        // ================= attention path =================
        const int ab = blockIdx.x;
        const int b = ab / 24, rem = ab % 24;
        const int h = rem / 3, qt3 = rem % 3;
        const int qg = wave;
        const size_t base = (size_t)(b * T_) * 1536 + h * 64;

        Frag qf0, qf1;
        {
            const float s = 0.125f * LOG2E;
            const float* qp = qkv + base + (size_t)(qt3 * 64 + qg * 16 + m16) * 1536 + quad * 8;
            float4 u0 = *(const float4*)qp;
            float4 u1 = *(const float4*)(qp + 4);
            float4 u2 = *(const float4*)(qp + 32);
            float4 u3 = *(const float4*)(qp + 36);
            qf0.i = (intx4){ (int)pack_rne(u0.x * s, u0.y * s), (int)pack_rne(u0.z * s, u0.w * s),
                             (int)pack_rne(u1.x * s, u1.y * s), (int)pack_rne(u1.z * s, u1.w * s) };
            qf1.i = (intx4){ (int)pack_rne(u2.x * s, u2.y * s), (int)pack_rne(u2.z * s, u2.w * s),
                             (int)pack_rne(u3.x * s, u3.y * s), (int)pack_rne(u3.z * s, u3.w * s) };
        }

        float rsum[4] = {0.f, 0.f, 0.f, 0.f};
        floatx4 acco[4];
#pragma unroll
        for (int dt = 0; dt < 4; ++dt) acco[dt] = (floatx4){0.f, 0.f, 0.f, 0.f};

        for (int p = 0; p < 2; ++p) {
            if (p) __syncthreads();
            for (int i = tid; i < 96 * 16; i += 256) {
                int row = i >> 4, c4 = (i & 15) << 2;
                const float* kp = qkv + base + (size_t)(p * 96 + row) * 1536 + 512 + c4;
                float4 kv = *(const float4*)kp;
                *(uint2*)&S.at.kp.Ks[row][c4] = make_uint2(pack_rne(kv.x, kv.y), pack_rne(kv.z, kv.w));
                float4 vv = *(const float4*)(qkv + base + (size_t)(p * 96 + row) * 1536 + 1024 + c4);
                S.at.Vt[c4 + 0][row] = bf16_rne(vv.x);
                S.at.Vt[c4 + 1][row] = bf16_rne(vv.y);
                S.at.Vt[c4 + 2][row] = bf16_rne(vv.z);
                S.at.Vt[c4 + 3][row] = bf16_rne(vv.w);
            }
            __syncthreads();

            float ev[6][4];
#pragma unroll
            for (int tt = 0; tt < 6; ++tt) {
                Frag kb0 = ld_frag8(&S.at.kp.Ks[tt * 16 + m16][quad * 8]);
                Frag kb1 = ld_frag8(&S.at.kp.Ks[tt * 16 + m16][32 + quad * 8]);
                floatx4 accs = (floatx4){0.f, 0.f, 0.f, 0.f};
                accs = mfma16(qf0, kb0, accs);
                accs = mfma16(qf1, kb1, accs);
#pragma unroll
                for (int rr = 0; rr < 4; ++rr) {
                    float e = fexp2(accs[rr]);
                    ev[tt][rr] = e;
                    rsum[rr] += e;
                }
            }
            __syncthreads();
#pragma unroll
            for (int tt = 0; tt < 6; ++tt)
#pragma unroll
                for (int rr = 0; rr < 4; ++rr)
                    S.at.kp.P[qg * 16 + quad * 4 + rr][tt * 16 + m16] = bf16_rne(ev[tt][rr]);
#pragma unroll
            for (int ts = 0; ts < 3; ++ts) {
                Frag pf = ld_frag8(&S.at.kp.P[qg * 16 + m16][ts * 32 + quad * 8]);
#pragma unroll
                for (int dt = 0; dt < 4; ++dt) {
                    Frag vf = ld_frag8(&S.at.Vt[dt * 16 + m16][ts * 32 + quad * 8]);
                    acco[dt] = mfma16(pf, vf, acco[dt]);
                }
            }
        }

        float rinv[4];
#pragma unroll
        for (int rr = 0; rr < 4; ++rr) {
            float v = rsum[rr];
            v += __shfl_xor(v, 1, 64);
            v += __shfl_xor(v, 2, 64);
            v += __shfl_xor(v, 4, 64);
            v += __shfl_xor(v, 8, 64);
            rinv[rr] = 1.0f / v;
        }
#pragma unroll
        for (int dt = 0; dt < 4; ++dt)
#pragma unroll
            for (int rr = 0; rr < 4; ++rr) {
                float o = acco[dt][rr] * rinv[rr];
                size_t idx = (size_t)(b * T_ + qt3 * 64 + qg * 16 + quad * 4 + rr) * 512
                           + h * 64 + dt * 16 + m16;
                aoh[idx] = bf16_rne(o);
            }
        return;
    }

    // ================= trittention path =================
    const int t2 = blockIdx.x - 96;
    const int xx = t2 % 96;
    const int h = (t2 / 96) % CH;
    const int b = t2 / (96 * CH);
    const int qt = xx >> 4;
    const int sc = (xx >> 2) & 3;
    const int tc = xx & 3;
    const int q0 = qt * 32, s0 = sc * 48, t0 = tc * 48;
    const int bh = b * CH + h;
    const size_t rowbase = (size_t)(b * T_) * 1280 + h * 64;
    const float kA = 0.015625f * LOG2E;

    for (int i = tid; i < 48 * 32; i += 256) {
        int row = i >> 5, cp = i & 31;
        const float2 va = *(const float2*)(proj + rowbase + (size_t)(s0 + row) * 1280 + 0 + cp * 2);
        S.tr.a_lds[row * 36 + cp] = pack_f16(va.x * kA, va.y * kA);
        const float2 vb = *(const float2*)(proj + rowbase + (size_t)(t0 + row) * 1280 + 256 + cp * 2);
        S.tr.b_lds[row * 36 + cp] = pack_f16(vb.x, vb.y);
    }

    FragH cf[2][2];
#pragma unroll
    for (int jq = 0; jq < 2; ++jq) {
        const float* cp = proj + rowbase + (size_t)(q0 + jq * 16 + m16) * 1280 + 512 + quad * 8;
        float4 u0 = *(const float4*)(cp);
        float4 u1 = *(const float4*)(cp + 4);
        float4 u2 = *(const float4*)(cp + 32);
        float4 u3 = *(const float4*)(cp + 36);
        cf[jq][0].i = (intx4){ (int)pack_f16(u0.x, u0.y), (int)pack_f16(u0.z, u0.w),
                               (int)pack_f16(u1.x, u1.y), (int)pack_f16(u1.z, u1.w) };
        cf[jq][1].i = (intx4){ (int)pack_f16(u2.x, u2.y), (int)pack_f16(u2.z, u2.w),
                               (int)pack_f16(u3.x, u3.y), (int)pack_f16(u3.z, u3.w) };
    }
    __syncthreads();

    float rt_acc[3][4][2] = {};

    for (int si = 0; si < 12; ++si) {
        const int srow = wave * 12 + si;
        const intx4 av0 = *(const intx4*)(S.tr.a_lds + srow * 36 + quad * 4);
        const intx4 av1 = *(const intx4*)(S.tr.a_lds + srow * 36 + 16 + quad * 4);
        float rs_s[2] = {0.f, 0.f};
#pragma unroll
        for (int tt = 0; tt < 3; ++tt) {
            const u32* bp2 = S.tr.b_lds + (tt * 16 + m16) * 36;
            intx4 bv0 = *(const intx4*)(bp2 + quad * 4);
            intx4 bv1 = *(const intx4*)(bp2 + 16 + quad * 4);
            FragH w0, w1;
#pragma unroll
            for (int j = 0; j < 4; ++j) {
                w0.i[j] = (int)mul_h2((u32)av0[j], (u32)bv0[j]);
                w1.i[j] = (int)mul_h2((u32)av1[j], (u32)bv1[j]);
            }
#pragma unroll
            for (int jq = 0; jq < 2; ++jq) {
                floatx4 acc = (floatx4){0.f, 0.f, 0.f, 0.f};
                acc = mfma16h(w0, cf[jq][0], acc);
                acc = mfma16h(w1, cf[jq][1], acc);
#pragma unroll
                for (int rr = 0; rr < 4; ++rr) {
                    float e = fexp2(acc[rr]);
                    rt_acc[tt][rr][jq] += e;
                    rs_s[jq] += e;
                }
            }
        }
#pragma unroll
        for (int jq = 0; jq < 2; ++jq) {
            float v = rs_s[jq];
            v += __shfl_xor(v, 16, 64);
            v += __shfl_xor(v, 32, 64);
            if (lane < 16) S.tr.rs_lds[srow][jq * 16 + m16] = v;
        }
    }

    __syncthreads();
    for (int w = 0; w < 4; ++w) {
        if (wave == w) {
#pragma unroll
            for (int tt = 0; tt < 3; ++tt)
#pragma unroll
                for (int rr = 0; rr < 4; ++rr) {
                    int t = tt * 16 + quad * 4 + rr;
#pragma unroll
                    for (int jq = 0; jq < 2; ++jq) {
                        if (w == 0) S.tr.rt_lds[t][jq * 16 + m16] = rt_acc[tt][rr][jq];
                        else        S.tr.rt_lds[t][jq * 16 + m16] += rt_acc[tt][rr][jq];
                    }
                }
        }
        __syncthreads();
    }
    for (int i = tid; i < 32 * 48; i += 256) {
        int qq = i / 48, ss = i - qq * 48;
        unsafeAtomicAdd(&rs1[((size_t)bh * T_ + q0 + qq) * T_ + s0 + ss], S.tr.rs_lds[ss][qq]);
    }
    for (int i = tid; i < 32 * 48; i += 256) {
        int qq = i / 48, t3 = i - qq * 48;
        unsafeAtomicAdd(&rt1[((size_t)bh * T_ + q0 + qq) * T_ + t0 + t3], S.tr.rt_lds[t3][qq]);
    }
}

// ---------------- Finale: A-blocks (0..191) ao@Wo^T+bias; B-blocks (192..287) zgemm+z@Wp^T --
__global__ __launch_bounds__(256) void finale(
    const u16* __restrict__ aoh, const float* __restrict__ rs1, const float* __restrict__ rt1,
    const float* __restrict__ proj, const u16* __restrict__ wofh,
    const float* __restrict__ bo, const float* __restrict__ bp,
    float* __restrict__ out)
{
    __shared__ union {
        struct { u16 As[32][68]; u16 Bs[64][68]; } A;
        struct { u16 Am[2][32][68]; u16 Bs[64][68]; float zred[32][9]; float Zl[32]; } B;
    } S;
    const int tid = threadIdx.x;
    const int lane = tid & 63, wave = tid >> 6;
    const int m16 = lane & 15, quad = lane >> 4;

    if (blockIdx.x < 192) {
        // ===== A: out += ao @ Wo^T + bo + bp  (M=768, N=512, K=512) =====
        const int bn = (blockIdx.x & 7) * 64, bm = (blockIdx.x >> 3) * 32;
        const int wm = (wave >> 1) * 16, wn = (wave & 1) * 32;
        const int ra = tid >> 3, c8 = (tid & 7) * 8;
        const int rb = tid >> 2, c16 = (tid & 3) * 16;

        floatx4 acc[2];
        acc[0] = (floatx4){0.f, 0.f, 0.f, 0.f};
        acc[1] = (floatx4){0.f, 0.f, 0.f, 0.f};

        for (int k0 = 0; k0 < 512; k0 += 64) {
            __syncthreads();
            {
                const u16* pah = aoh + (size_t)(bm + ra) * 512 + k0 + c8;
                uint4 v = *(const uint4*)pah;
                *(uint2*)&S.A.As[ra][c8 + 0] = make_uint2(v.x, v.y);
                *(uint2*)&S.A.As[ra][c8 + 4] = make_uint2(v.z, v.w);
            }
            {
                const u16* pb = wofh + (size_t)(bn + rb) * 768 + k0 + c16;
                uint4 v0 = *(const uint4*)pb, v1 = *(const uint4*)(pb + 8);
                *(uint2*)&S.A.Bs[rb][c16 + 0]  = make_uint2(v0.x, v0.y);
                *(uint2*)&S.A.Bs[rb][c16 + 4]  = make_uint2(v0.z, v0.w);
                *(uint2*)&S.A.Bs[rb][c16 + 8]  = make_uint2(v1.x, v1.y);
                *(uint2*)&S.A.Bs[rb][c16 + 12] = make_uint2(v1.z, v1.w);
            }
            __syncthreads();
#pragma unroll
            for (int ks = 0; ks < 2; ++ks) {
                const int ko = ks * 32 + quad * 8;
                Frag ah = ld_frag8(&S.A.As[wm + m16][ko]);
                Frag b0 = ld_frag8(&S.A.Bs[wn + m16][ko]);
                Frag b1 = ld_frag8(&S.A.Bs[wn + 16 + m16][ko]);
                acc[0] = mfma16(ah, b0, acc[0]);
                acc[1] = mfma16(ah, b1, acc[1]);
            }
        }
#pragma unroll
        for (int rr = 0; rr < 4; ++rr) {
            int m = bm + wm + quad * 4 + rr;
#pragma unroll
            for (int j = 0; j < 2; ++j) {
                int n = bn + wn + j * 16 + m16;
                unsafeAtomicAdd(&out[(size_t)m * 512 + n], acc[j][rr] + bo[n] + bp[n]);
            }
        }
        return;
    }

    // ===== B: zgemm (z in registers) then out += z @ Wp^T =====
    const int blockB = blockIdx.x - 192;
    const int mt = blockB % 6, bh = blockB / 6;
    const int b = bh >> 2, h = bh & 3;
    const int q0 = mt * 32;
    const int wm = (wave >> 1) * 16, wn = (wave & 1) * 32;
    const int ra = tid >> 3, c8 = (tid & 7) * 8;
    const int sl = tid >> 2, d4b = (tid & 3) * 4;

    float zacc = 0.f;
    floatx4 acc[2];
    acc[0] = (floatx4){0.f, 0.f, 0.f, 0.f};
    acc[1] = (floatx4){0.f, 0.f, 0.f, 0.f};

    for (int k0 = 0; k0 < 384; k0 += 64) {
        __syncthreads();
        {
            float g[8];
            if (k0 < 192) {
                const float* p = rs1 + ((size_t)bh * T_ + q0 + ra) * T_ + k0 + c8;
                float4 v0 = *(const float4*)(p);
                float4 v1 = *(const float4*)(p + 4);
                g[0] = v0.x; g[1] = v0.y; g[2] = v0.z; g[3] = v0.w;
                g[4] = v1.x; g[5] = v1.y; g[6] = v1.z; g[7] = v1.w;
                zacc += ((g[0] + g[1]) + (g[2] + g[3])) + ((g[4] + g[5]) + (g[6] + g[7]));
            } else {
                const float* p = rt1 + ((size_t)bh * T_ + q0 + ra) * T_ + (k0 - 192) + c8;
                float4 v0 = *(const float4*)(p);
                float4 v1 = *(const float4*)(p + 4);
                g[0] = v0.x; g[1] = v0.y; g[2] = v0.z; g[3] = v0.w;
                g[4] = v1.x; g[5] = v1.y; g[6] = v1.z; g[7] = v1.w;
            }
#pragma unroll
            for (int i = 0; i < 8; ++i) {
                u16 hi = bf16_rne(g[i]);
                S.B.Am[0][ra][c8 + i] = hi;
                S.B.Am[1][ra][c8 + i] = bf16_rne(g[i] - bf16f(hi));
            }
        }
        {
            const int colbase = (k0 < 192 ? 768 : 1024) + h * 64;
            const int s0 = (k0 < 192 ? k0 : k0 - 192);
#pragma unroll
            for (int i = 0; i < 4; ++i) {
                int dd = d4b + i * 16;
                float4 v = *(const float4*)(proj + (size_t)(b * T_ + s0 + sl) * 1280 + colbase + dd);
                S.B.Bs[dd + 0][sl] = bf16_rne(v.x);
                S.B.Bs[dd + 1][sl] = bf16_rne(v.y);
                S.B.Bs[dd + 2][sl] = bf16_rne(v.z);
                S.B.Bs[dd + 3][sl] = bf16_rne(v.w);
            }
        }
        __syncthreads();
#pragma unroll
        for (int ks = 0; ks < 2; ++ks) {
            const int ko = ks * 32 + quad * 8;
            Frag gh = ld_frag8(&S.B.Am[0][wm + m16][ko]);
            Frag gl = ld_frag8(&S.B.Am[1][wm + m16][ko]);
            Frag d0 = ld_frag8(&S.B.Bs[wn + m16][ko]);
            Frag d1 = ld_frag8(&S.B.Bs[wn + 16 + m16][ko]);
            acc[0] = mfma16(gh, d0, acc[0]);
            acc[0] = mfma16(gl, d0, acc[0]);
            acc[1] = mfma16(gh, d1, acc[1]);
            acc[1] = mfma16(gl, d1, acc[1]);
        }
    }
    S.B.zred[ra][tid & 7] = zacc;
    __syncthreads();
    if (tid < 32) {
        float s = ((S.B.zred[tid][0] + S.B.zred[tid][1]) + (S.B.zred[tid][2] + S.B.zred[tid][3]))
                + ((S.B.zred[tid][4] + S.B.zred[tid][5]) + (S.B.zred[tid][6] + S.B.zred[tid][7]));
        S.B.Zl[tid] = 1.0f / s;
    }
    __syncthreads();
    // normalized z tile -> LDS bf16 (reuse Am[0] as z_s[32][68]); then z @ Wp^T scatter
    {
        float zv[2][4];
#pragma unroll
        for (int j = 0; j < 2; ++j)
#pragma unroll
            for (int rr = 0; rr < 4; ++rr) {
                int m = wm + quad * 4 + rr;
                zv[j][rr] = acc[j][rr] * S.B.Zl[m];
            }
        __syncthreads();
#pragma unroll
        for (int j = 0; j < 2; ++j)
#pragma unroll
            for (int rr = 0; rr < 4; ++rr) {
                int m = wm + quad * 4 + rr;
                int d = wn + j * 16 + m16;
                S.B.Am[0][m][d] = bf16_rne(zv[j][rr]);
            }
    }
    __syncthreads();
#pragma unroll
    for (int t = 0; t < 8; ++t) {
        const int n0 = wave * 128 + t * 16;
        Frag bf0 = ld_frag8(&wofh[(size_t)(n0 + m16) * 768 + 512 + h * 64 + quad * 8]);
        Frag bf1 = ld_frag8(&wofh[(size_t)(n0 + m16) * 768 + 512 + h * 64 + 32 + quad * 8]);
#pragma unroll
        for (int qi = 0; qi < 2; ++qi) {
            Frag za = ld_frag8(&S.B.Am[0][qi * 16 + m16][quad * 8]);
            Frag zb = ld_frag8(&S.B.Am[0][qi * 16 + m16][32 + quad * 8]);
            floatx4 ac = (floatx4){0.f, 0.f, 0.f, 0.f};
            ac = mfma16(za, bf0, ac);
            ac = mfma16(zb, bf1, ac);
#pragma unroll
            for (int rr = 0; rr < 4; ++rr) {
                int m = b * T_ + q0 + qi * 16 + quad * 4 + rr;
                unsafeAtomicAdd(&out[(size_t)m * 512 + n0 + m16], ac[rr]);
            }
        }
    }
}

extern "C" void kernel_launch(void* const* d_in, const int* in_sizes, int n_in,
                              void* d_out, int out_size, void* d_ws, size_t ws_size,
                              hipStream_t stream)
{
    const float* x      = (const float*)d_in[0];
    const float* ln1_g  = (const float*)d_in[1];
    const float* ln1_b  = (const float*)d_in[2];
    const float* Wqkv   = (const float*)d_in[3];
    const float* Wo     = (const float*)d_in[4];
    const float* bo     = (const float*)d_in[5];
    const float* ln2_g  = (const float*)d_in[6];
    const float* ln2_b  = (const float*)d_in[7];
    const float* Wabcde = (const float*)d_in[8];
    const float* babcde = (const float*)d_in[9];
    const float* Wp     = (const float*)d_in[10];
    const float* bp     = (const float*)d_in[11];
    float* out = (float*)d_out;

    // ---- workspace layout (f32 units) — NO aliasing ----
    float* ws   = (float*)d_ws;
    float* proj = ws;                              // 983,040 f
    u16* wofh   = (u16*)(ws + 983040);             // 393,216 u16
    u16* aoh    = (u16*)(ws + 1179648);            // 393,216 u16
    float* qkv  = ws + 1376256;                    // 1,179,648 f
    u16* x1h    = (u16*)(ws + 2555904);            // 393,216 u16
    u16* x2h    = (u16*)(ws + 2752512);            // 393,216 u16
    u16* wqh    = (u16*)(ws + 2949120);            // 786,432 u16
    u16* wah    = (u16*)(ws + 3342336);            // 655,360 u16
    float* rs1  = ws + 3670016;                    // 589,824 f (zeroed by prep)
    float* rt1  = ws + 4259840;                    // 589,824 f (contiguous after rs1)

    prep_kernel<<<1216, 256, 0, stream>>>(x, ln1_g, ln1_b, ln2_g, ln2_b,
                                          x1h, x2h,
                                          Wqkv, wqh, Wabcde, wah,
                                          Wo, Wp, wofh, rs1, out);
    gemm_dual<<<dim3(44, 12), 256, 0, stream>>>(x1h, wqh, x2h, wah,
                                                babcde, qkv, proj);
    attn_tritt<<<96 + 1536, 256, 0, stream>>>(qkv, proj, aoh, rs1, rt1);
    finale<<<288, 256, 0, stream>>>(aoh, rs1, rt1, proj, wofh, bo, bp, out);
}